// Round 3
// baseline (1456.579 us; speedup 1.0000x reference)
//
#include <hip/hip_runtime.h>
#include <stdint.h>

#define DEVI __device__ __forceinline__
typedef unsigned long long ull;

typedef __bf16 bf16x8 __attribute__((ext_vector_type(8)));
typedef float floatx4 __attribute__((ext_vector_type(4)));
typedef unsigned int u32x4 __attribute__((ext_vector_type(4)));

// ---------- helpers ----------
DEVI uint16_t f2bf(float f) {
  union { float f; uint32_t u; } c; c.f = f;
  uint32_t u = c.u;
  return (uint16_t)((u + 0x7fffu + ((u >> 16) & 1u)) >> 16);  // RNE
}
DEVI float bf2f(uint16_t h) {
  union { uint32_t u; float f; } c; c.u = ((uint32_t)h) << 16;
  return c.f;
}
DEVI void load_lds_16(const void* g, void* l) {
  __builtin_amdgcn_global_load_lds(
      (const __attribute__((address_space(1))) void*)g,
      (__attribute__((address_space(3))) void*)l, 16, 0, 0);
}
DEVI float sigm(float x) { return 1.f / (1.f + __expf(-x)); }
DEVI float tanh_s(float x) {
  float xc = fminf(fmaxf(x, -15.f), 15.f);
  float e = __expf(2.f * xc);
  return (e - 1.f) / (e + 1.f);
}
// bypass (write-through, no L2 alloc) stores: producer data lands at the
// coherence point, so vmcnt(0)+flag is a sound agent-release without wbl2.
DEVI void bypass_store_u16(uint16_t* p, uint32_t v) {
  asm volatile("global_store_short %0, %1, off sc0 sc1" :: "v"(p), "v"(v) : "memory");
}
DEVI void bypass_store_u32(unsigned* p, uint32_t v) {
  asm volatile("global_store_dword %0, %1, off sc0 sc1" :: "v"(p), "v"(v) : "memory");
}

// ---------- workspace layout (bytes) ----------
// pre [256][64][2048] bf16 — producer-written (bypass), consumer-read (cached),
// NEVER aliased/clobbered this round.
// h-exchange: dedicated depth-2 ring at OFF_RING (2 x 262144). Slot t&1 written
// at step t (tag t+1), polled at step t+1 (want t+1... i.e. poll want == step).
// Depth-2 safety: poll(t) success => all same-bg peers finished epilogue(t-1)
// => finished poll(t-1) => nobody still reads the slot we overwrite at step t.
// dcnt[128] at OFF_CNT: per-Mb producer completion counters (16 tiles each).
static constexpr size_t OFF_EMB    = 0;                        // [50000][256] bf16
static constexpr size_t OFF_WXT    = 25600000;                 // [2048][4096] bf16
static constexpr size_t OFF_WHT    = OFF_WXT + 16777216;       // [2048][512] bf16
static constexpr size_t OFF_BIAS   = OFF_WHT + 2097152;        // [2048] f32
static constexpr size_t OFF_PRE    = OFF_BIAS + 8192;          // [256][64][2048] bf16
static constexpr size_t OFF_HF     = OFF_PRE + 67108864 + 4096;
static constexpr size_t OFF_CF     = OFF_HF + 131072;
static constexpr size_t OFF_CNT    = OFF_CF + 131072;          // dcnt[128]
static constexpr size_t OFF_RING   = OFF_CNT + 4096;           // 2 x 262144 (poison != tag)

// ---------- 1. embedding -> bf16, row 0 zeroed ----------
__global__ __launch_bounds__(256) void k_emb_cvt(const float* __restrict__ emb,
                                                 uint16_t* __restrict__ dst) {
  size_t tid = (size_t)blockIdx.x * 256 + threadIdx.x;
  size_t e = tid * 8;
  int v = (int)(e >> 8);
  const float4* s = (const float4*)(emb + e);
  float4 f0 = s[0], f1 = s[1];
  if (v == 0) { f0 = make_float4(0.f, 0.f, 0.f, 0.f); f1 = f0; }
  uint32_t w0 = f2bf(f0.x) | ((uint32_t)f2bf(f0.y) << 16);
  uint32_t w1 = f2bf(f0.z) | ((uint32_t)f2bf(f0.w) << 16);
  uint32_t w2 = f2bf(f1.x) | ((uint32_t)f2bf(f1.y) << 16);
  uint32_t w3 = f2bf(f1.z) | ((uint32_t)f2bf(f1.w) << 16);
  *(uint4*)(dst + e) = make_uint4(w0, w1, w2, w3);
}

// ---------- 2. weight transpose+convert: W_g[K][512] -> dst[n=h*4+g][K] bf16 ----------
__global__ __launch_bounds__(256) void k_wt(const float* __restrict__ w0, const float* __restrict__ w1,
                                            const float* __restrict__ w2, const float* __restrict__ w3,
                                            int K, uint16_t* __restrict__ dst) {
  __shared__ float tile[64 * 64];
  int k0 = blockIdx.x * 64;
  int n0 = blockIdx.y * 64;
  int h0 = blockIdx.y * 16;
  int g = threadIdx.x >> 6, di = threadIdx.x & 63;
  const float* w = (g == 0) ? w0 : (g == 1) ? w1 : (g == 2) ? w2 : w3;
  const float4* src = (const float4*)(w + (size_t)(k0 + di) * 512 + h0);
  float4 a = src[0], b = src[1], c = src[2], d = src[3];
  float vals[16] = {a.x, a.y, a.z, a.w, b.x, b.y, b.z, b.w,
                    c.x, c.y, c.z, c.w, d.x, d.y, d.z, d.w};
#pragma unroll
  for (int dh = 0; dh < 16; ++dh) tile[(dh * 4 + g) * 64 + di] = vals[dh];
  __syncthreads();
  int nl = threadIdx.x >> 2, ch = threadIdx.x & 3;
  uint32_t wb[8];
#pragma unroll
  for (int j = 0; j < 8; ++j) {
    float lo = tile[nl * 64 + ch * 16 + j * 2];
    float hi = tile[nl * 64 + ch * 16 + j * 2 + 1];
    wb[j] = f2bf(lo) | ((uint32_t)f2bf(hi) << 16);
  }
  uint4* dp = (uint4*)(dst + (size_t)(n0 + nl) * K + k0 + ch * 16);
  dp[0] = make_uint4(wb[0], wb[1], wb[2], wb[3]);
  dp[1] = make_uint4(wb[4], wb[5], wb[6], wb[7]);
}

// ---------- 3. bias pack + dcnt zeroing (bypass: zeros land at coherence point) ----------
__global__ __launch_bounds__(256) void k_bias(const float* __restrict__ b0, const float* __restrict__ b1,
                                              const float* __restrict__ b2, const float* __restrict__ b3,
                                              float* __restrict__ dst, unsigned* __restrict__ dcnt) {
  int n = blockIdx.x * 256 + threadIdx.x;
  if (n < 128) bypass_store_u32(dcnt + n, 0u);
  int h = n >> 2, g = n & 3;
  const float* b = (g == 0) ? b0 : (g == 1) ? b1 : (g == 2) ? b2 : b3;
  dst[n] = b[h];
}

// ---------- 4+5 fused: static-partition gather-GEMM producers + recurrence consumers ----------
// grid = 640 WGs: bids 0..63 = recurrence (4 bg x 16 cg), bids 64..639 = 576
// producers, producer p owns tiles {p, p+576, ...} (ascending => ascending Mb).
// LDS 42.5KB -> 3 WG/CU -> 768 resident slots >= 640. Producers never wait;
// every consumer wait is fuel-bounded => kernel cannot hang.
__global__ __launch_bounds__(256) void k_fused(const uint16_t* __restrict__ embbf,
                                               const int* __restrict__ x,
                                               const uint16_t* __restrict__ wxt,
                                               uint16_t* pre,
                                               char* ring,
                                               const uint16_t* __restrict__ wht,
                                               const float* __restrict__ biasp,
                                               float* __restrict__ hfin,
                                               float* __restrict__ cfin,
                                               unsigned* dcnt) {
  __shared__ __align__(16) char smem[42240];
  const int tid = threadIdx.x;

  if (blockIdx.x >= 64) {
    // ================= gather-GEMM producer (proven k_gemm body) =================
    uint16_t* As = (uint16_t*)smem;
    uint16_t* Bs = (uint16_t*)(smem + 16384);
    const int wv = tid >> 6, ln = tid & 63;
    const int wm = wv >> 1, wn = wv & 1;
    const int srow = ln >> 3, schunk = ln & 7;
    const int q = ln >> 4, l16 = ln & 15;

    uint16_t* ldsA[4];
    uint16_t* ldsB[4];
#pragma unroll
    for (int j = 0; j < 4; ++j) {
      ldsA[j] = As + (j * 32 + wv * 8) * 64;
      ldsB[j] = Bs + (j * 32 + wv * 8) * 64;
    }
    int aoff[4], boff[4];
#pragma unroll
    for (int mt = 0; mt < 4; ++mt) aoff[mt] = (wm * 64 + mt * 16 + l16) * 64 + q * 8;
#pragma unroll
    for (int nt = 0; nt < 4; ++nt) boff[nt] = (wn * 64 + nt * 16 + l16) * 64 + q * 8;

    for (unsigned tile = (unsigned)(blockIdx.x - 64); tile < 2048u; tile += 576u) {
      const int Mb = (int)(tile >> 4), Nb = (int)(tile & 15u);
      const int M0 = Mb * 128, N0 = Nb * 128;

      const int* xrow[4];
      const uint16_t* bbase[4];
#pragma unroll
      for (int j = 0; j < 4; ++j) {
        int r = j * 32 + wv * 8 + srow;
        int m = M0 + r;
        int t = m >> 6, b = m & 63;
        xrow[j] = x + b * 4096 + t;
        bbase[j] = wxt + (size_t)(N0 + r) * 4096 + schunk * 8;
      }

      floatx4 acc[4][4] = {};

      for (int p = 0; p < 16; ++p) {
        const uint16_t* abase[4];
#pragma unroll
        for (int j = 0; j < 4; ++j) {
          int idx = xrow[j][p << 8];
          abase[j] = embbf + (size_t)idx * 256 + schunk * 8;
        }
#pragma unroll 1
        for (int ki = 0; ki < 4; ++ki) {
          __syncthreads();
#pragma unroll
          for (int j = 0; j < 4; ++j) load_lds_16(abase[j] + ki * 64, ldsA[j]);
#pragma unroll
          for (int j = 0; j < 4; ++j) load_lds_16(bbase[j] + p * 256 + ki * 64, ldsB[j]);
          __syncthreads();
#pragma unroll
          for (int kk = 0; kk < 2; ++kk) {
            bf16x8 a[4];
#pragma unroll
            for (int mt = 0; mt < 4; ++mt) a[mt] = *(const bf16x8*)(As + aoff[mt] + kk * 32);
#pragma unroll
            for (int nt = 0; nt < 4; ++nt) {
              bf16x8 bv = *(const bf16x8*)(Bs + boff[nt] + kk * 32);
#pragma unroll
              for (int mt = 0; mt < 4; ++mt)
                acc[mt][nt] = __builtin_amdgcn_mfma_f32_16x16x32_bf16(a[mt], bv, acc[mt][nt], 0, 0, 0);
            }
          }
        }
      }

      // epilogue: bypass stores -> vmcnt(0) -> WG barrier -> dcnt release
#pragma unroll
      for (int mt = 0; mt < 4; ++mt) {
        int mg = M0 + wm * 64 + mt * 16 + q * 4;
#pragma unroll
        for (int nt = 0; nt < 4; ++nt) {
          int ng = N0 + wn * 64 + nt * 16 + l16;
#pragma unroll
          for (int r = 0; r < 4; ++r)
            bypass_store_u16(pre + (size_t)(mg + r) * 2048 + ng, (uint32_t)f2bf(acc[mt][nt][r]));
        }
      }
      asm volatile("s_waitcnt vmcnt(0)" ::: "memory");
      __syncthreads();
      if (tid == 0)
        __hip_atomic_fetch_add(&dcnt[Mb], 1u, __ATOMIC_RELAXED, __HIP_MEMORY_SCOPE_AGENT);
    }
    return;
  }

  // ================= recurrence consumer (proven body + ring + bounded gate) =================
  uint16_t (*Ahs)[16 * 528] = (uint16_t (*)[16 * 528])smem;  // stride 528: conflict-free
  float* gates = (float*)(smem + 33792);

  const int wv = tid >> 6, ln = tid & 63;
  const int q = ln >> 4, l16 = ln & 15;
  const int bg = blockIdx.x >> 4, cg = blockIdx.x & 15;
  const int N0 = cg * 128;

  // B fragments resident: wave wv owns n-cols N0 + wv*32 .. +32
  bf16x8 Bfrag[16][2];
#pragma unroll
  for (int kc = 0; kc < 16; ++kc)
#pragma unroll
    for (int nt = 0; nt < 2; ++nt) {
      int n = N0 + wv * 32 + nt * 16 + l16;
      Bfrag[kc][nt] = *(const bf16x8*)(wht + (size_t)n * 512 + kc * 32 + q * 8);
    }
  float breg[2];
#pragma unroll
  for (int nt = 0; nt < 2; ++nt) breg[nt] = biasp[N0 + wv * 32 + nt * 16 + l16];

  const int prow = tid >> 4;                // poll row 0..15
  const int pseg = tid & 15;                // 16B segment within 256B chunk
  const int erow = ln >> 2;
  const int es = ln & 3;
  float creg[2] = {0.f, 0.f};

  // zero Ahs[0] (t=0 state h=0)
  for (int i = tid; i < 4224; i += 256) ((uint32_t*)Ahs[0])[i] = 0;

  // monotone producer frontier: all Mb <= frontier are fully at the coherence
  // point. Fuel-bounded: on starvation we proceed (wrong data beats a hang —
  // the bench then reports absmax instead of timing out opaquely).
  int frontier = -1;
  auto gate = [&](int m) {
    int fuel = 1 << 13;
    while (frontier < m) {
      uint32_t v;
      asm volatile("global_load_dword %0, %1, off sc0 sc1\n\t"
                   "s_waitcnt vmcnt(0)"
                   : "=v"(v) : "v"(dcnt + (frontier + 1)) : "memory");
      if (v >= 16u) { ++frontier; continue; }
      if (--fuel <= 0) { ++frontier; continue; }
      __builtin_amdgcn_s_sleep(2);
    }
  };

  gate(0);
  // register prefetch of pre strip for t=0 (gated -> produced; L2 was
  // invalidated at dispatch start, and nothing fills pre lines pre-production)
  uint16_t pr[8];
#pragma unroll
  for (int nt = 0; nt < 2; ++nt)
#pragma unroll
    for (int r = 0; r < 4; ++r)
      pr[nt * 4 + r] = pre[(size_t)(bg * 16 + q * 4 + r) * 2048 + N0 + wv * 32 + nt * 16 + l16];

  for (int t = 0; t < 256; ++t) {
    if (t > 0) {
      const char* sb = ring + (size_t)((t - 1) & 1) * 262144 + (size_t)bg * 65536;
      const char* base = sb + prow * 2048 + pseg * 16;
      const uint32_t want = (uint32_t)t;
      u32x4 u0, u1, u2, u3, u4, u5, u6, u7;
      int pfuel = 1 << 13;
      for (;;) {
        asm volatile(
            "global_load_dwordx4 %0, %8, off sc0 sc1\n\t"
            "global_load_dwordx4 %1, %8, off offset:256 sc0 sc1\n\t"
            "global_load_dwordx4 %2, %8, off offset:512 sc0 sc1\n\t"
            "global_load_dwordx4 %3, %8, off offset:768 sc0 sc1\n\t"
            "global_load_dwordx4 %4, %8, off offset:1024 sc0 sc1\n\t"
            "global_load_dwordx4 %5, %8, off offset:1280 sc0 sc1\n\t"
            "global_load_dwordx4 %6, %8, off offset:1536 sc0 sc1\n\t"
            "global_load_dwordx4 %7, %8, off offset:1792 sc0 sc1\n\t"
            "s_waitcnt vmcnt(0)"
            : "=v"(u0), "=v"(u1), "=v"(u2), "=v"(u3),
              "=v"(u4), "=v"(u5), "=v"(u6), "=v"(u7)
            : "v"(base)
            : "memory");
        bool ok = (u0.y == want) && (u0.w == want) && (u1.y == want) && (u1.w == want) &&
                  (u2.y == want) && (u2.w == want) && (u3.y == want) && (u3.w == want) &&
                  (u4.y == want) && (u4.w == want) && (u5.y == want) && (u5.w == want) &&
                  (u6.y == want) && (u6.w == want) && (u7.y == want) && (u7.w == want);
        if (ok) break;
        if (--pfuel <= 0) break;
        __builtin_amdgcn_s_sleep(1);
      }
      // stage payloads: col = 4*pseg + 64*j, contiguous 4 cols per u32x4
      uint16_t* dr = Ahs[t & 1] + prow * 528 + pseg * 4;
      *(ull*)(dr +   0) = (ull)u0.x | ((ull)u0.z << 32);
      *(ull*)(dr +  64) = (ull)u1.x | ((ull)u1.z << 32);
      *(ull*)(dr + 128) = (ull)u2.x | ((ull)u2.z << 32);
      *(ull*)(dr + 192) = (ull)u3.x | ((ull)u3.z << 32);
      *(ull*)(dr + 256) = (ull)u4.x | ((ull)u4.z << 32);
      *(ull*)(dr + 320) = (ull)u5.x | ((ull)u5.z << 32);
      *(ull*)(dr + 384) = (ull)u6.x | ((ull)u6.z << 32);
      *(ull*)(dr + 448) = (ull)u7.x | ((ull)u7.z << 32);
    }
    __syncthreads();  // the one barrier per step

    // MFMA [16 x 512] x [512 x 32] per wave, 2 chains of 8
    const uint16_t* Ab = Ahs[t & 1];
    floatx4 a0[2] = {}, a1[2] = {};
#pragma unroll
    for (int kc = 0; kc < 8; ++kc) {
      bf16x8 a = *(const bf16x8*)(Ab + l16 * 528 + kc * 32 + q * 8);
#pragma unroll
      for (int nt = 0; nt < 2; ++nt)
        a0[nt] = __builtin_amdgcn_mfma_f32_16x16x32_bf16(a, Bfrag[kc][nt], a0[nt], 0, 0, 0);
    }
#pragma unroll
    for (int kc = 8; kc < 16; ++kc) {
      bf16x8 a = *(const bf16x8*)(Ab + l16 * 528 + kc * 32 + q * 8);
#pragma unroll
      for (int nt = 0; nt < 2; ++nt)
        a1[nt] = __builtin_amdgcn_mfma_f32_16x16x32_bf16(a, Bfrag[kc][nt], a1[nt], 0, 0, 0);
    }

    // gates = acc + bias + pre (registers, wave-local columns)
#pragma unroll
    for (int nt = 0; nt < 2; ++nt) {
      int n_l = wv * 32 + nt * 16 + l16;
      floatx4 s = a0[nt] + a1[nt];
#pragma unroll
      for (int r = 0; r < 4; ++r) {
        int row = q * 4 + r;
        gates[row * 132 + n_l] = s[r] + breg[nt] + bf2f(pr[nt * 4 + r]);
      }
    }
    // wave-local LDS exchange: compiler inserts lgkmcnt wait, no barrier

    // epilogue: 2 h-units per lane; tagged 8B agent store into ring[t&1]
    {
      float4 v0 = *(const float4*)(gates + erow * 132 + wv * 32 + es * 8);
      float4 v1 = *(const float4*)(gates + erow * 132 + wv * 32 + es * 8 + 4);
      float f0 = sigm(v0.x), i0 = sigm(v0.y), g0 = tanh_s(v0.z), o0 = sigm(v0.w);
      float f1 = sigm(v1.x), i1 = sigm(v1.y), g1 = tanh_s(v1.z), o1 = sigm(v1.w);
      float c0 = f0 * creg[0] + i0 * g0; creg[0] = c0;
      float c1 = f1 * creg[1] + i1 * g1; creg[1] = c1;
      float h0 = o0 * tanh_s(c0), h1 = o1 * tanh_s(c1);
      char* sbw = ring + (size_t)(t & 1) * 262144 + (size_t)bg * 65536;
      int pair = cg * 16 + wv * 4 + es;
      ull pk = (ull)((uint32_t)f2bf(h0) | ((uint32_t)f2bf(h1) << 16)) |
               ((ull)(uint32_t)(t + 1) << 32);
      __hip_atomic_store((ull*)(sbw + erow * 2048 + pair * 8),
                         pk, __ATOMIC_RELAXED, __HIP_MEMORY_SCOPE_AGENT);
      if (t == 255) {
        size_t idx = (size_t)(bg * 16 + erow) * 512 + cg * 32 + wv * 8 + es * 2;
        hfin[idx] = h0; hfin[idx + 1] = h1;
        cfin[idx] = c0; cfin[idx + 1] = c1;
      }
    }

    // register prefetch of pre strip for t+1, gated on producer frontier
    if (t < 255) {
      int tn = t + 1;
      gate(tn >> 1);
#pragma unroll
      for (int nt = 0; nt < 2; ++nt)
#pragma unroll
        for (int r = 0; r < 4; ++r)
          pr[nt * 4 + r] = pre[(size_t)(tn * 64 + bg * 16 + q * 4 + r) * 2048 + N0 + wv * 32 + nt * 16 + l16];
    }
  }
}

// ---------- 6. final: out = h @ W_lin + b_lin; copy h, c ----------
__global__ __launch_bounds__(256) void k_final(const float* __restrict__ h, const float* __restrict__ c,
                                               const float* __restrict__ wl, const float* __restrict__ bl,
                                               float* __restrict__ out) {
  __shared__ float red[256];
  int b = blockIdx.x, t = threadIdx.x;
  const float* hb = h + (size_t)b * 512;
  if (t < 128) {
    ((float4*)(out + 320 + (size_t)b * 512))[t] = ((const float4*)hb)[t];
    ((float4*)(out + 320 + 32768 + (size_t)b * 512))[t] = ((const float4*)(c + (size_t)b * 512))[t];
  }
  float h0 = hb[t], h1 = hb[t + 256];
  for (int o = 0; o < 5; ++o) {
    red[t] = h0 * wl[t * 5 + o] + h1 * wl[(t + 256) * 5 + o];
    __syncthreads();
    for (int s = 128; s > 0; s >>= 1) {
      if (t < s) red[t] += red[t + s];
      __syncthreads();
    }
    if (t == 0) out[b * 5 + o] = red[0] + bl[o];
    __syncthreads();
  }
}

// ---------- launch ----------
extern "C" void kernel_launch(void* const* d_in, const int* in_sizes, int n_in,
                              void* d_out, int out_size, void* d_ws, size_t ws_size,
                              hipStream_t stream) {
  const int*   x   = (const int*)d_in[0];
  const float* emb = (const float*)d_in[1];
  const float* wfx = (const float*)d_in[2];
  const float* wfh = (const float*)d_in[3];
  const float* bf_ = (const float*)d_in[4];
  const float* wix = (const float*)d_in[5];
  const float* wih = (const float*)d_in[6];
  const float* bi_ = (const float*)d_in[7];
  const float* wgx = (const float*)d_in[8];
  const float* wgh = (const float*)d_in[9];
  const float* bg_ = (const float*)d_in[10];
  const float* wox = (const float*)d_in[11];
  const float* woh = (const float*)d_in[12];
  const float* bo_ = (const float*)d_in[13];
  const float* wl  = (const float*)d_in[14];
  const float* bl  = (const float*)d_in[15];
  float* out = (float*)d_out;
  char* ws = (char*)d_ws;

  uint16_t* embbf = (uint16_t*)(ws + OFF_EMB);
  uint16_t* wxt   = (uint16_t*)(ws + OFF_WXT);
  uint16_t* wht   = (uint16_t*)(ws + OFF_WHT);
  float*    bias  = (float*)(ws + OFF_BIAS);
  uint16_t* pre   = (uint16_t*)(ws + OFF_PRE);
  float*    hfin  = (float*)(ws + OFF_HF);
  float*    cfin  = (float*)(ws + OFF_CF);
  unsigned* dcnt  = (unsigned*)(ws + OFF_CNT);

  hipLaunchKernelGGL(k_emb_cvt, dim3(6250), dim3(256), 0, stream, emb, embbf);
  hipLaunchKernelGGL(k_wt, dim3(64, 32), dim3(256), 0, stream, wfx, wix, wgx, wox, 4096, wxt);
  hipLaunchKernelGGL(k_wt, dim3(8, 32), dim3(256), 0, stream, wfh, wih, wgh, woh, 512, wht);
  hipLaunchKernelGGL(k_bias, dim3(8), dim3(256), 0, stream, bf_, bi_, bg_, bo_, bias, dcnt);
  hipLaunchKernelGGL(k_fused, dim3(640), dim3(256), 0, stream, embbf, x, wxt, pre,
                     ws + OFF_RING, wht, bias, hfin, cfin, dcnt);
  hipLaunchKernelGGL(k_final, dim3(64), dim3(256), 0, stream, hfin, cfin, wl, bl, out);
}

// Round 5
// 1426.340 us; speedup vs baseline: 1.0212x; 1.0212x over previous
//
#include <hip/hip_runtime.h>
#include <stdint.h>

#define DEVI __device__ __forceinline__
typedef unsigned long long ull;

typedef __bf16 bf16x8 __attribute__((ext_vector_type(8)));
typedef float floatx4 __attribute__((ext_vector_type(4)));
typedef unsigned int u32x4 __attribute__((ext_vector_type(4)));

// ---------- helpers ----------
DEVI uint16_t f2bf(float f) {
  union { float f; uint32_t u; } c; c.f = f;
  uint32_t u = c.u;
  return (uint16_t)((u + 0x7fffu + ((u >> 16) & 1u)) >> 16);  // RNE
}
DEVI float bf2f(uint16_t h) {
  union { uint32_t u; float f; } c; c.u = ((uint32_t)h) << 16;
  return c.f;
}
DEVI void load_lds_16(const void* g, void* l) {
  __builtin_amdgcn_global_load_lds(
      (const __attribute__((address_space(1))) void*)g,
      (__attribute__((address_space(3))) void*)l, 16, 0, 0);
}
DEVI float sigm(float x) { return 1.f / (1.f + __expf(-x)); }
DEVI float tanh_s(float x) {
  float xc = fminf(fmaxf(x, -15.f), 15.f);
  float e = __expf(2.f * xc);
  return (e - 1.f) / (e + 1.f);
}
DEVI void bypass_store_u32(unsigned* p, uint32_t v) {
  asm volatile("global_store_dword %0, %1, off sc0 sc1" :: "v"(p), "v"(v) : "memory");
}

// ---------- workspace layout (bytes) ----------
// pre [256][64][2048] bf16 — serial k_gemm writes (cached, dispatch-boundary
// flush), k_rec reads cached. Dedicated depth-2 h-ring at OFF_RING (2x262144):
// step t writes ring[t&1] (tag t+1, device-scope 8B atomic store), polls
// ring[(t-1)&1] for tag t. Proven in round 3. Claim block at OFF_CNT:
// claim[0..7] per-XCD bucket counters, claim[16..17] = 64-bit role map.
static constexpr size_t OFF_EMB    = 0;                        // [50000][256] bf16
static constexpr size_t OFF_WXT    = 25600000;                 // [2048][4096] bf16
static constexpr size_t OFF_WHT    = OFF_WXT + 16777216;       // [2048][512] bf16
static constexpr size_t OFF_BIAS   = OFF_WHT + 2097152;        // [2048] f32
static constexpr size_t OFF_PRE    = OFF_BIAS + 8192;          // [256][64][2048] bf16
static constexpr size_t OFF_HF     = OFF_PRE + 67108864 + 4096;
static constexpr size_t OFF_CF     = OFF_HF + 131072;
static constexpr size_t OFF_CNT    = OFF_CF + 131072;          // claim[] + map
static constexpr size_t OFF_RING   = OFF_CNT + 4096;           // 2 x 262144 (poison != tag)

// ---------- 1. embedding -> bf16, row 0 zeroed ----------
__global__ __launch_bounds__(256) void k_emb_cvt(const float* __restrict__ emb,
                                                 uint16_t* __restrict__ dst) {
  size_t tid = (size_t)blockIdx.x * 256 + threadIdx.x;
  size_t e = tid * 8;
  int v = (int)(e >> 8);
  const float4* s = (const float4*)(emb + e);
  float4 f0 = s[0], f1 = s[1];
  if (v == 0) { f0 = make_float4(0.f, 0.f, 0.f, 0.f); f1 = f0; }
  uint32_t w0 = f2bf(f0.x) | ((uint32_t)f2bf(f0.y) << 16);
  uint32_t w1 = f2bf(f0.z) | ((uint32_t)f2bf(f0.w) << 16);
  uint32_t w2 = f2bf(f1.x) | ((uint32_t)f2bf(f1.y) << 16);
  uint32_t w3 = f2bf(f1.z) | ((uint32_t)f2bf(f1.w) << 16);
  *(uint4*)(dst + e) = make_uint4(w0, w1, w2, w3);
}

// ---------- 2. weight transpose+convert: W_g[K][512] -> dst[n=h*4+g][K] bf16 ----------
__global__ __launch_bounds__(256) void k_wt(const float* __restrict__ w0, const float* __restrict__ w1,
                                            const float* __restrict__ w2, const float* __restrict__ w3,
                                            int K, uint16_t* __restrict__ dst) {
  __shared__ float tile[64 * 64];
  int k0 = blockIdx.x * 64;
  int n0 = blockIdx.y * 64;
  int h0 = blockIdx.y * 16;
  int g = threadIdx.x >> 6, di = threadIdx.x & 63;
  const float* w = (g == 0) ? w0 : (g == 1) ? w1 : (g == 2) ? w2 : w3;
  const float4* src = (const float4*)(w + (size_t)(k0 + di) * 512 + h0);
  float4 a = src[0], b = src[1], c = src[2], d = src[3];
  float vals[16] = {a.x, a.y, a.z, a.w, b.x, b.y, b.z, b.w,
                    c.x, c.y, c.z, c.w, d.x, d.y, d.z, d.w};
#pragma unroll
  for (int dh = 0; dh < 16; ++dh) tile[(dh * 4 + g) * 64 + di] = vals[dh];
  __syncthreads();
  int nl = threadIdx.x >> 2, ch = threadIdx.x & 3;
  uint32_t wb[8];
#pragma unroll
  for (int j = 0; j < 8; ++j) {
    float lo = tile[nl * 64 + ch * 16 + j * 2];
    float hi = tile[nl * 64 + ch * 16 + j * 2 + 1];
    wb[j] = f2bf(lo) | ((uint32_t)f2bf(hi) << 16);
  }
  uint4* dp = (uint4*)(dst + (size_t)(n0 + nl) * K + k0 + ch * 16);
  dp[0] = make_uint4(wb[0], wb[1], wb[2], wb[3]);
  dp[1] = make_uint4(wb[4], wb[5], wb[6], wb[7]);
}

// ---------- 3. bias pack + claim zeroing (bypass: at coherence point) ----------
__global__ __launch_bounds__(256) void k_bias(const float* __restrict__ b0, const float* __restrict__ b1,
                                              const float* __restrict__ b2, const float* __restrict__ b3,
                                              float* __restrict__ dst, unsigned* __restrict__ claim) {
  int n = blockIdx.x * 256 + threadIdx.x;
  if (n < 24) bypass_store_u32(claim + n, 0u);  // buckets[8] + pad + map[2]
  int h = n >> 2, g = n & 3;
  const float* b = (g == 0) ? b0 : (g == 1) ? b1 : (g == 2) ? b2 : b3;
  dst[n] = b[h];
}

// ---------- 4. gather-GEMM (proven baseline, cached stores) ----------
__global__ __launch_bounds__(256) void k_gemm(const uint16_t* __restrict__ embbf,
                                              const int* __restrict__ x,
                                              const uint16_t* __restrict__ wxt,
                                              uint16_t* __restrict__ pre) {
  __shared__ uint16_t As[128 * 64];
  __shared__ uint16_t Bs[128 * 64];
  const int tid = threadIdx.x;
  const int wv = tid >> 6, ln = tid & 63;
  const int wm = wv >> 1, wn = wv & 1;
  const int M0 = blockIdx.x * 128, N0 = blockIdx.y * 128;
  const int srow = ln >> 3, schunk = ln & 7;

  const int* xrow[4];
  const uint16_t* bbase[4];
  uint16_t* ldsA[4];
  uint16_t* ldsB[4];
#pragma unroll
  for (int j = 0; j < 4; ++j) {
    int r = j * 32 + wv * 8 + srow;
    int m = M0 + r;
    int t = m >> 6, b = m & 63;
    xrow[j] = x + b * 4096 + t;
    bbase[j] = wxt + (size_t)(N0 + r) * 4096 + schunk * 8;
    ldsA[j] = As + (j * 32 + wv * 8) * 64;
    ldsB[j] = Bs + (j * 32 + wv * 8) * 64;
  }

  const int q = ln >> 4, l16 = ln & 15;
  int aoff[4], boff[4];
#pragma unroll
  for (int mt = 0; mt < 4; ++mt) aoff[mt] = (wm * 64 + mt * 16 + l16) * 64 + q * 8;
#pragma unroll
  for (int nt = 0; nt < 4; ++nt) boff[nt] = (wn * 64 + nt * 16 + l16) * 64 + q * 8;

  floatx4 acc[4][4] = {};

  for (int p = 0; p < 16; ++p) {
    const uint16_t* abase[4];
#pragma unroll
    for (int j = 0; j < 4; ++j) {
      int idx = xrow[j][p << 8];
      abase[j] = embbf + (size_t)idx * 256 + schunk * 8;
    }
#pragma unroll 1
    for (int ki = 0; ki < 4; ++ki) {
      __syncthreads();
#pragma unroll
      for (int j = 0; j < 4; ++j) load_lds_16(abase[j] + ki * 64, ldsA[j]);
#pragma unroll
      for (int j = 0; j < 4; ++j) load_lds_16(bbase[j] + p * 256 + ki * 64, ldsB[j]);
      __syncthreads();
#pragma unroll
      for (int kk = 0; kk < 2; ++kk) {
        bf16x8 a[4];
#pragma unroll
        for (int mt = 0; mt < 4; ++mt) a[mt] = *(const bf16x8*)(As + aoff[mt] + kk * 32);
#pragma unroll
        for (int nt = 0; nt < 4; ++nt) {
          bf16x8 bv = *(const bf16x8*)(Bs + boff[nt] + kk * 32);
#pragma unroll
          for (int mt = 0; mt < 4; ++mt)
            acc[mt][nt] = __builtin_amdgcn_mfma_f32_16x16x32_bf16(a[mt], bv, acc[mt][nt], 0, 0, 0);
        }
      }
    }
  }

#pragma unroll
  for (int mt = 0; mt < 4; ++mt) {
    int mg = M0 + wm * 64 + mt * 16 + q * 4;
#pragma unroll
    for (int nt = 0; nt < 4; ++nt) {
      int ng = N0 + wn * 64 + nt * 16 + l16;
#pragma unroll
      for (int r = 0; r < 4; ++r)
        pre[(size_t)(mg + r) * 2048 + ng] = f2bf(acc[mt][nt][r]);
    }
  }
}

// ---------- 5. recurrence: co-located exchange, scope-hazard-proof ----------
// 512 WGs; role claim = per-XCD bucket slot + global 64-bit map bit (atomicOr).
// Map guarantees: exactly one owner per role, all 64 roles owned (reserves
// sweep leftovers after a grace wait). Stores: device-scope 8B atomic (proven).
// Polls: 3x sc0 rounds (local-L2 fast path when co-located; harmless stale L1
// hit otherwise) + every 4th round sc0 sc1 authoritative (guarantees progress
// under ANY scope semantics). Fuel-bounded => cannot hang.
__global__ __launch_bounds__(256) void k_rec(const uint16_t* __restrict__ pre,
                                             char* ring,
                                             const uint16_t* __restrict__ wht,
                                             const float* __restrict__ biasp,
                                             float* __restrict__ hfin,
                                             float* __restrict__ cfin,
                                             unsigned* claim) {
  __shared__ uint16_t Ahs[2][16 * 528];     // stride 528: conflict-free b64 writes + b128 reads
  __shared__ float gates[16 * 132];
  __shared__ int s_role;

  const int tid = threadIdx.x;

  if (tid == 0) {
    uint32_t xcc;
    asm volatile("s_getreg_b32 %0, hwreg(HW_REG_XCC_ID)" : "=s"(xcc));
    xcc &= 15u;
    int role = -1;
    ull* map = (ull*)(claim + 16);
    if (xcc < 4u) {
      unsigned slot = atomicAdd(&claim[xcc], 1u);
      if (slot < 16u) {
        int r = (int)(xcc * 16u + slot);
        ull old = atomicOr(map, 1ull << r);
        if (!((old >> r) & 1ull)) role = r;
      }
    }
    if (role < 0) {
      // reserve: grace-wait for locals, then sweep unclaimed roles (rare)
      ull m = 0;
      for (int g = 0; g < 1024; ++g) {
        m = __hip_atomic_load(map, __ATOMIC_RELAXED, __HIP_MEMORY_SCOPE_AGENT);
        if (m == ~0ull) break;
        __builtin_amdgcn_s_sleep(8);
      }
      if (m != ~0ull) {
        for (int r = 0; r < 64 && role < 0; ++r) {
          if (!((m >> r) & 1ull)) {
            ull old = atomicOr(map, 1ull << r);
            if (!((old >> r) & 1ull)) role = r;
            else m = old;
          }
        }
      }
    }
    s_role = role;
  }
  __syncthreads();
  const int role = s_role;
  if (role < 0) return;
  const int bg = role >> 4, cg = role & 15;
  const int N0 = cg * 128;

  const int wv = tid >> 6, ln = tid & 63;
  const int q = ln >> 4, l16 = ln & 15;

  // B fragments: wave wv owns n-cols N0 + wv*32 .. +32
  bf16x8 Bfrag[16][2];
#pragma unroll
  for (int kc = 0; kc < 16; ++kc)
#pragma unroll
    for (int nt = 0; nt < 2; ++nt) {
      int n = N0 + wv * 32 + nt * 16 + l16;
      Bfrag[kc][nt] = *(const bf16x8*)(wht + (size_t)n * 512 + kc * 32 + q * 8);
    }
  float breg[2];
#pragma unroll
  for (int nt = 0; nt < 2; ++nt) breg[nt] = biasp[N0 + wv * 32 + nt * 16 + l16];

  const int prow = tid >> 4;                // poll row 0..15
  const int pseg = tid & 15;                // 16B segment within 256B chunk
  const int erow = ln >> 2;
  const int es = ln & 3;
  float creg[2] = {0.f, 0.f};

  // zero Ahs[0] (t=0 state h=0)
  for (int i = tid; i < 4224; i += 256) ((uint32_t*)Ahs[0])[i] = 0;

  // register prefetch of pre strip for t=0
  uint16_t pr[8];
#pragma unroll
  for (int nt = 0; nt < 2; ++nt)
#pragma unroll
    for (int r = 0; r < 4; ++r)
      pr[nt * 4 + r] = pre[(size_t)(bg * 16 + q * 4 + r) * 2048 + N0 + wv * 32 + nt * 16 + l16];

  for (int t = 0; t < 256; ++t) {
    if (t > 0) {
      const char* sb = ring + (size_t)((t - 1) & 1) * 262144 + (size_t)bg * 65536;
      const char* base = sb + prow * 2048 + pseg * 16;
      const uint32_t want = (uint32_t)t;
      u32x4 u0, u1, u2, u3, u4, u5, u6, u7;
      int pfuel = 1 << 13;
      for (int it = 0;; ++it) {
        if ((it & 3) != 3) {
          asm volatile(
              "global_load_dwordx4 %0, %8, off sc0\n\t"
              "global_load_dwordx4 %1, %8, off offset:256 sc0\n\t"
              "global_load_dwordx4 %2, %8, off offset:512 sc0\n\t"
              "global_load_dwordx4 %3, %8, off offset:768 sc0\n\t"
              "global_load_dwordx4 %4, %8, off offset:1024 sc0\n\t"
              "global_load_dwordx4 %5, %8, off offset:1280 sc0\n\t"
              "global_load_dwordx4 %6, %8, off offset:1536 sc0\n\t"
              "global_load_dwordx4 %7, %8, off offset:1792 sc0\n\t"
              "s_waitcnt vmcnt(0)"
              : "=v"(u0), "=v"(u1), "=v"(u2), "=v"(u3),
                "=v"(u4), "=v"(u5), "=v"(u6), "=v"(u7)
              : "v"(base)
              : "memory");
        } else {
          asm volatile(
              "global_load_dwordx4 %0, %8, off sc0 sc1\n\t"
              "global_load_dwordx4 %1, %8, off offset:256 sc0 sc1\n\t"
              "global_load_dwordx4 %2, %8, off offset:512 sc0 sc1\n\t"
              "global_load_dwordx4 %3, %8, off offset:768 sc0 sc1\n\t"
              "global_load_dwordx4 %4, %8, off offset:1024 sc0 sc1\n\t"
              "global_load_dwordx4 %5, %8, off offset:1280 sc0 sc1\n\t"
              "global_load_dwordx4 %6, %8, off offset:1536 sc0 sc1\n\t"
              "global_load_dwordx4 %7, %8, off offset:1792 sc0 sc1\n\t"
              "s_waitcnt vmcnt(0)"
              : "=v"(u0), "=v"(u1), "=v"(u2), "=v"(u3),
                "=v"(u4), "=v"(u5), "=v"(u6), "=v"(u7)
              : "v"(base)
              : "memory");
        }
        bool ok = (u0.y == want) && (u0.w == want) && (u1.y == want) && (u1.w == want) &&
                  (u2.y == want) && (u2.w == want) && (u3.y == want) && (u3.w == want) &&
                  (u4.y == want) && (u4.w == want) && (u5.y == want) && (u5.w == want) &&
                  (u6.y == want) && (u6.w == want) && (u7.y == want) && (u7.w == want);
        if (ok) break;
        if (--pfuel <= 0) break;
        if ((it & 3) == 3) __builtin_amdgcn_s_sleep(1);
      }
      // stage payloads: col = 4*pseg + 64*j, contiguous 4 cols per u32x4
      uint16_t* dr = Ahs[t & 1] + prow * 528 + pseg * 4;
      *(ull*)(dr +   0) = (ull)u0.x | ((ull)u0.z << 32);
      *(ull*)(dr +  64) = (ull)u1.x | ((ull)u1.z << 32);
      *(ull*)(dr + 128) = (ull)u2.x | ((ull)u2.z << 32);
      *(ull*)(dr + 192) = (ull)u3.x | ((ull)u3.z << 32);
      *(ull*)(dr + 256) = (ull)u4.x | ((ull)u4.z << 32);
      *(ull*)(dr + 320) = (ull)u5.x | ((ull)u5.z << 32);
      *(ull*)(dr + 384) = (ull)u6.x | ((ull)u6.z << 32);
      *(ull*)(dr + 448) = (ull)u7.x | ((ull)u7.z << 32);
    }
    __syncthreads();  // the one barrier per step

    // MFMA [16 x 512] x [512 x 32] per wave, 2 chains of 8
    const uint16_t* Ab = Ahs[t & 1];
    floatx4 a0[2] = {}, a1[2] = {};
#pragma unroll
    for (int kc = 0; kc < 8; ++kc) {
      bf16x8 a = *(const bf16x8*)(Ab + l16 * 528 + kc * 32 + q * 8);
#pragma unroll
      for (int nt = 0; nt < 2; ++nt)
        a0[nt] = __builtin_amdgcn_mfma_f32_16x16x32_bf16(a, Bfrag[kc][nt], a0[nt], 0, 0, 0);
    }
#pragma unroll
    for (int kc = 8; kc < 16; ++kc) {
      bf16x8 a = *(const bf16x8*)(Ab + l16 * 528 + kc * 32 + q * 8);
#pragma unroll
      for (int nt = 0; nt < 2; ++nt)
        a1[nt] = __builtin_amdgcn_mfma_f32_16x16x32_bf16(a, Bfrag[kc][nt], a1[nt], 0, 0, 0);
    }

    // gates = acc + bias + pre (registers, wave-local columns)
#pragma unroll
    for (int nt = 0; nt < 2; ++nt) {
      int n_l = wv * 32 + nt * 16 + l16;
      floatx4 s = a0[nt] + a1[nt];
#pragma unroll
      for (int r = 0; r < 4; ++r) {
        int row = q * 4 + r;
        gates[row * 132 + n_l] = s[r] + breg[nt] + bf2f(pr[nt * 4 + r]);
      }
    }
    // wave-local LDS exchange: compiler inserts lgkmcnt wait, no barrier

    // epilogue: 2 h-units per lane; tagged 8B device-scope store into ring[t&1]
    {
      float4 v0 = *(const float4*)(gates + erow * 132 + wv * 32 + es * 8);
      float4 v1 = *(const float4*)(gates + erow * 132 + wv * 32 + es * 8 + 4);
      float f0 = sigm(v0.x), i0 = sigm(v0.y), g0 = tanh_s(v0.z), o0 = sigm(v0.w);
      float f1 = sigm(v1.x), i1 = sigm(v1.y), g1 = tanh_s(v1.z), o1 = sigm(v1.w);
      float c0 = f0 * creg[0] + i0 * g0; creg[0] = c0;
      float c1 = f1 * creg[1] + i1 * g1; creg[1] = c1;
      float h0 = o0 * tanh_s(c0), h1 = o1 * tanh_s(c1);
      char* sbw = ring + (size_t)(t & 1) * 262144 + (size_t)bg * 65536;
      int pair = cg * 16 + wv * 4 + es;
      ull pk = (ull)((uint32_t)f2bf(h0) | ((uint32_t)f2bf(h1) << 16)) |
               ((ull)(uint32_t)(t + 1) << 32);
      __hip_atomic_store((ull*)(sbw + erow * 2048 + pair * 8),
                         pk, __ATOMIC_RELAXED, __HIP_MEMORY_SCOPE_AGENT);
      if (t == 255) {
        size_t idx = (size_t)(bg * 16 + erow) * 512 + cg * 32 + wv * 8 + es * 2;
        hfin[idx] = h0; hfin[idx + 1] = h1;
        cfin[idx] = c0; cfin[idx + 1] = c1;
      }
    }

    // register prefetch of pre strip for t+1 (hidden under next poll window)
    if (t < 255) {
      int tn = t + 1;
#pragma unroll
      for (int nt = 0; nt < 2; ++nt)
#pragma unroll
        for (int r = 0; r < 4; ++r)
          pr[nt * 4 + r] = pre[(size_t)(tn * 64 + bg * 16 + q * 4 + r) * 2048 + N0 + wv * 32 + nt * 16 + l16];
    }
  }
}

// ---------- 6. final: out = h @ W_lin + b_lin; copy h, c ----------
__global__ __launch_bounds__(256) void k_final(const float* __restrict__ h, const float* __restrict__ c,
                                               const float* __restrict__ wl, const float* __restrict__ bl,
                                               float* __restrict__ out) {
  __shared__ float red[256];
  int b = blockIdx.x, t = threadIdx.x;
  const float* hb = h + (size_t)b * 512;
  if (t < 128) {
    ((float4*)(out + 320 + (size_t)b * 512))[t] = ((const float4*)hb)[t];
    ((float4*)(out + 320 + 32768 + (size_t)b * 512))[t] = ((const float4*)(c + (size_t)b * 512))[t];
  }
  float h0 = hb[t], h1 = hb[t + 256];
  for (int o = 0; o < 5; ++o) {
    red[t] = h0 * wl[t * 5 + o] + h1 * wl[(t + 256) * 5 + o];
    __syncthreads();
    for (int s = 128; s > 0; s >>= 1) {
      if (t < s) red[t] += red[t + s];
      __syncthreads();
    }
    if (t == 0) out[b * 5 + o] = red[0] + bl[o];
    __syncthreads();
  }
}

// ---------- launch ----------
extern "C" void kernel_launch(void* const* d_in, const int* in_sizes, int n_in,
                              void* d_out, int out_size, void* d_ws, size_t ws_size,
                              hipStream_t stream) {
  const int*   x   = (const int*)d_in[0];
  const float* emb = (const float*)d_in[1];
  const float* wfx = (const float*)d_in[2];
  const float* wfh = (const float*)d_in[3];
  const float* bf_ = (const float*)d_in[4];
  const float* wix = (const float*)d_in[5];
  const float* wih = (const float*)d_in[6];
  const float* bi_ = (const float*)d_in[7];
  const float* wgx = (const float*)d_in[8];
  const float* wgh = (const float*)d_in[9];
  const float* bg_ = (const float*)d_in[10];
  const float* wox = (const float*)d_in[11];
  const float* woh = (const float*)d_in[12];
  const float* bo_ = (const float*)d_in[13];
  const float* wl  = (const float*)d_in[14];
  const float* bl  = (const float*)d_in[15];
  float* out = (float*)d_out;
  char* ws = (char*)d_ws;

  uint16_t* embbf = (uint16_t*)(ws + OFF_EMB);
  uint16_t* wxt   = (uint16_t*)(ws + OFF_WXT);
  uint16_t* wht   = (uint16_t*)(ws + OFF_WHT);
  float*    bias  = (float*)(ws + OFF_BIAS);
  uint16_t* pre   = (uint16_t*)(ws + OFF_PRE);
  float*    hfin  = (float*)(ws + OFF_HF);
  float*    cfin  = (float*)(ws + OFF_CF);
  unsigned* claim = (unsigned*)(ws + OFF_CNT);

  hipLaunchKernelGGL(k_emb_cvt, dim3(6250), dim3(256), 0, stream, emb, embbf);
  hipLaunchKernelGGL(k_wt, dim3(64, 32), dim3(256), 0, stream, wfx, wix, wgx, wox, 4096, wxt);
  hipLaunchKernelGGL(k_wt, dim3(8, 32), dim3(256), 0, stream, wfh, wih, wgh, woh, 512, wht);
  hipLaunchKernelGGL(k_bias, dim3(8), dim3(256), 0, stream, bf_, bi_, bg_, bo_, bias, claim);
  hipLaunchKernelGGL(k_gemm, dim3(128, 16), dim3(256), 0, stream, embbf, x, wxt, pre);
  hipLaunchKernelGGL(k_rec, dim3(512), dim3(256), 0, stream, pre, ws + OFF_RING,
                     wht, bias, hfin, cfin, claim);
  hipLaunchKernelGGL(k_final, dim3(64), dim3(256), 0, stream, hfin, cfin, wl, bl, out);
}

// Round 6
// 1204.692 us; speedup vs baseline: 1.2091x; 1.1840x over previous
//
#include <hip/hip_runtime.h>
#include <stdint.h>

#define DEVI __device__ __forceinline__
typedef unsigned long long ull;

typedef __bf16 bf16x8 __attribute__((ext_vector_type(8)));
typedef float floatx4 __attribute__((ext_vector_type(4)));
typedef unsigned int u32x4 __attribute__((ext_vector_type(4)));

// ---------- helpers ----------
DEVI uint16_t f2bf(float f) {
  union { float f; uint32_t u; } c; c.f = f;
  uint32_t u = c.u;
  return (uint16_t)((u + 0x7fffu + ((u >> 16) & 1u)) >> 16);  // RNE
}
DEVI float bf2f(uint16_t h) {
  union { uint32_t u; float f; } c; c.u = ((uint32_t)h) << 16;
  return c.f;
}
DEVI void load_lds_16(const void* g, void* l) {
  __builtin_amdgcn_global_load_lds(
      (const __attribute__((address_space(1))) void*)g,
      (__attribute__((address_space(3))) void*)l, 16, 0, 0);
}
DEVI float sigm(float x) { return 1.f / (1.f + __expf(-x)); }
DEVI float tanh_s(float x) {
  float xc = fminf(fmaxf(x, -15.f), 15.f);
  float e = __expf(2.f * xc);
  return (e - 1.f) / (e + 1.f);
}
// bypass (write-through, no L2 alloc) stores: producer data lands at the
// coherence point, so vmcnt(0)+flag is a sound agent-release without wbl2.
DEVI void bypass_store_u16(uint16_t* p, uint32_t v) {
  asm volatile("global_store_short %0, %1, off sc0 sc1" :: "v"(p), "v"(v) : "memory");
}
DEVI void bypass_store_u32(unsigned* p, uint32_t v) {
  asm volatile("global_store_dword %0, %1, off sc0 sc1" :: "v"(p), "v"(v) : "memory");
}

// ---------- workspace layout (bytes) ----------
// pre [256][64][2048] bf16 — producer-written (bypass), consumer-read (cached:
// consumer L2 invalidated at dispatch start, bypass stores live at coherence
// point, so cached misses fetch fresh). NEVER aliased.
// h-exchange: dedicated depth-2 ring at OFF_RING (2 x 262144). Step t writes
// ring[t&1] (tag t+1, device-scope 8B atomic), polls ring[(t-1)&1] for tag t.
// Depth-2 safety: poll(t) success => all same-bg peers finished epilogue(t-1)
// => finished poll(t-1) => nobody still reads the slot overwritten at step t.
// (Cross-iteration stale tags cleared by harness workspace re-poison.)
// dcnt[128] at OFF_CNT: per-Mb producer completion counters (16 tiles each).
// Lesson bank (r4/r5): sc0-only exchange is unsound AND slow on gfx950 —
// agent stores don't refresh reader-side cache lines; only full-bypass polls
// make progress. All cross-WG polling below is sc0 sc1.
static constexpr size_t OFF_EMB    = 0;                        // [50000][256] bf16
static constexpr size_t OFF_WXT    = 25600000;                 // [2048][4096] bf16
static constexpr size_t OFF_WHT    = OFF_WXT + 16777216;       // [2048][512] bf16
static constexpr size_t OFF_BIAS   = OFF_WHT + 2097152;        // [2048] f32
static constexpr size_t OFF_PRE    = OFF_BIAS + 8192;          // [256][64][2048] bf16
static constexpr size_t OFF_HF     = OFF_PRE + 67108864 + 4096;
static constexpr size_t OFF_CF     = OFF_HF + 131072;
static constexpr size_t OFF_CNT    = OFF_CF + 131072;          // dcnt[128]
static constexpr size_t OFF_RING   = OFF_CNT + 4096;           // 2 x 262144 (poison != tag)

// ---------- 1. embedding -> bf16, row 0 zeroed ----------
__global__ __launch_bounds__(256) void k_emb_cvt(const float* __restrict__ emb,
                                                 uint16_t* __restrict__ dst) {
  size_t tid = (size_t)blockIdx.x * 256 + threadIdx.x;
  size_t e = tid * 8;
  int v = (int)(e >> 8);
  const float4* s = (const float4*)(emb + e);
  float4 f0 = s[0], f1 = s[1];
  if (v == 0) { f0 = make_float4(0.f, 0.f, 0.f, 0.f); f1 = f0; }
  uint32_t w0 = f2bf(f0.x) | ((uint32_t)f2bf(f0.y) << 16);
  uint32_t w1 = f2bf(f0.z) | ((uint32_t)f2bf(f0.w) << 16);
  uint32_t w2 = f2bf(f1.x) | ((uint32_t)f2bf(f1.y) << 16);
  uint32_t w3 = f2bf(f1.z) | ((uint32_t)f2bf(f1.w) << 16);
  *(uint4*)(dst + e) = make_uint4(w0, w1, w2, w3);
}

// ---------- 2. weight transpose+convert: W_g[K][512] -> dst[n=h*4+g][K] bf16 ----------
__global__ __launch_bounds__(256) void k_wt(const float* __restrict__ w0, const float* __restrict__ w1,
                                            const float* __restrict__ w2, const float* __restrict__ w3,
                                            int K, uint16_t* __restrict__ dst) {
  __shared__ float tile[64 * 64];
  int k0 = blockIdx.x * 64;
  int n0 = blockIdx.y * 64;
  int h0 = blockIdx.y * 16;
  int g = threadIdx.x >> 6, di = threadIdx.x & 63;
  const float* w = (g == 0) ? w0 : (g == 1) ? w1 : (g == 2) ? w2 : w3;
  const float4* src = (const float4*)(w + (size_t)(k0 + di) * 512 + h0);
  float4 a = src[0], b = src[1], c = src[2], d = src[3];
  float vals[16] = {a.x, a.y, a.z, a.w, b.x, b.y, b.z, b.w,
                    c.x, c.y, c.z, c.w, d.x, d.y, d.z, d.w};
#pragma unroll
  for (int dh = 0; dh < 16; ++dh) tile[(dh * 4 + g) * 64 + di] = vals[dh];
  __syncthreads();
  int nl = threadIdx.x >> 2, ch = threadIdx.x & 3;
  uint32_t wb[8];
#pragma unroll
  for (int j = 0; j < 8; ++j) {
    float lo = tile[nl * 64 + ch * 16 + j * 2];
    float hi = tile[nl * 64 + ch * 16 + j * 2 + 1];
    wb[j] = f2bf(lo) | ((uint32_t)f2bf(hi) << 16);
  }
  uint4* dp = (uint4*)(dst + (size_t)(n0 + nl) * K + k0 + ch * 16);
  dp[0] = make_uint4(wb[0], wb[1], wb[2], wb[3]);
  dp[1] = make_uint4(wb[4], wb[5], wb[6], wb[7]);
}

// ---------- 3. bias pack + dcnt zeroing (bypass: zeros at coherence point) ----------
__global__ __launch_bounds__(256) void k_bias(const float* __restrict__ b0, const float* __restrict__ b1,
                                              const float* __restrict__ b2, const float* __restrict__ b3,
                                              float* __restrict__ dst, unsigned* __restrict__ dcnt) {
  int n = blockIdx.x * 256 + threadIdx.x;
  if (n < 128) bypass_store_u32(dcnt + n, 0u);
  int h = n >> 2, g = n & 3;
  const float* b = (g == 0) ? b0 : (g == 1) ? b1 : (g == 2) ? b2 : b3;
  dst[n] = b[h];
}

// ---------- 4+5 fused, drain-and-join: one-shot GEMM producers + rec consumers ----------
// grid = 2048 WGs: bids 0..63 = recurrence (4 bg x 16 cg, dispatched first =>
// resident from t=0), bids 64..2047 = producers, each owning tile (bid-64)
// and (bid-64)+1984 if <2048 (Mb = tile>>4 ascending with bid => ascending-t
// completion). Producers EXIT after their tile(s): contention on rec decays as
// the GEMM drains (~1/3 of the dispatch), unlike r3's persistent producers.
// Producers never wait; consumer waits fuel-bounded => cannot hang.
__global__ __launch_bounds__(256) void k_fused(const uint16_t* __restrict__ embbf,
                                               const int* __restrict__ x,
                                               const uint16_t* __restrict__ wxt,
                                               uint16_t* pre,
                                               char* ring,
                                               const uint16_t* __restrict__ wht,
                                               const float* __restrict__ biasp,
                                               float* __restrict__ hfin,
                                               float* __restrict__ cfin,
                                               unsigned* dcnt) {
  __shared__ __align__(16) char smem[42240];
  const int tid = threadIdx.x;

  if (blockIdx.x >= 64) {
    // ================= one/two-tile gather-GEMM producer (proven body) =================
    uint16_t* As = (uint16_t*)smem;
    uint16_t* Bs = (uint16_t*)(smem + 16384);
    const int wv = tid >> 6, ln = tid & 63;
    const int wm = wv >> 1, wn = wv & 1;
    const int srow = ln >> 3, schunk = ln & 7;
    const int q = ln >> 4, l16 = ln & 15;

    uint16_t* ldsA[4];
    uint16_t* ldsB[4];
#pragma unroll
    for (int j = 0; j < 4; ++j) {
      ldsA[j] = As + (j * 32 + wv * 8) * 64;
      ldsB[j] = Bs + (j * 32 + wv * 8) * 64;
    }
    int aoff[4], boff[4];
#pragma unroll
    for (int mt = 0; mt < 4; ++mt) aoff[mt] = (wm * 64 + mt * 16 + l16) * 64 + q * 8;
#pragma unroll
    for (int nt = 0; nt < 4; ++nt) boff[nt] = (wn * 64 + nt * 16 + l16) * 64 + q * 8;

    for (unsigned tile = (unsigned)(blockIdx.x - 64); tile < 2048u; tile += 1984u) {
      const int Mb = (int)(tile >> 4), Nb = (int)(tile & 15u);
      const int M0 = Mb * 128, N0 = Nb * 128;

      const int* xrow[4];
      const uint16_t* bbase[4];
#pragma unroll
      for (int j = 0; j < 4; ++j) {
        int r = j * 32 + wv * 8 + srow;
        int m = M0 + r;
        int t = m >> 6, b = m & 63;
        xrow[j] = x + b * 4096 + t;
        bbase[j] = wxt + (size_t)(N0 + r) * 4096 + schunk * 8;
      }

      floatx4 acc[4][4] = {};

      for (int p = 0; p < 16; ++p) {
        const uint16_t* abase[4];
#pragma unroll
        for (int j = 0; j < 4; ++j) {
          int idx = xrow[j][p << 8];
          abase[j] = embbf + (size_t)idx * 256 + schunk * 8;
        }
#pragma unroll 1
        for (int ki = 0; ki < 4; ++ki) {
          __syncthreads();
#pragma unroll
          for (int j = 0; j < 4; ++j) load_lds_16(abase[j] + ki * 64, ldsA[j]);
#pragma unroll
          for (int j = 0; j < 4; ++j) load_lds_16(bbase[j] + p * 256 + ki * 64, ldsB[j]);
          __syncthreads();
#pragma unroll
          for (int kk = 0; kk < 2; ++kk) {
            bf16x8 a[4];
#pragma unroll
            for (int mt = 0; mt < 4; ++mt) a[mt] = *(const bf16x8*)(As + aoff[mt] + kk * 32);
#pragma unroll
            for (int nt = 0; nt < 4; ++nt) {
              bf16x8 bv = *(const bf16x8*)(Bs + boff[nt] + kk * 32);
#pragma unroll
              for (int mt = 0; mt < 4; ++mt)
                acc[mt][nt] = __builtin_amdgcn_mfma_f32_16x16x32_bf16(a[mt], bv, acc[mt][nt], 0, 0, 0);
            }
          }
        }
      }

      // epilogue: bypass stores -> vmcnt(0) -> WG barrier -> dcnt release
#pragma unroll
      for (int mt = 0; mt < 4; ++mt) {
        int mg = M0 + wm * 64 + mt * 16 + q * 4;
#pragma unroll
        for (int nt = 0; nt < 4; ++nt) {
          int ng = N0 + wn * 64 + nt * 16 + l16;
#pragma unroll
          for (int r = 0; r < 4; ++r)
            bypass_store_u16(pre + (size_t)(mg + r) * 2048 + ng, (uint32_t)f2bf(acc[mt][nt][r]));
        }
      }
      asm volatile("s_waitcnt vmcnt(0)" ::: "memory");
      __syncthreads();
      if (tid == 0)
        __hip_atomic_fetch_add(&dcnt[Mb], 1u, __ATOMIC_RELAXED, __HIP_MEMORY_SCOPE_AGENT);
    }
    return;  // producer exits -> frees its CU slot for the recurrence
  }

  // ================= recurrence consumer (proven body + ring + bounded gate) =================
  uint16_t (*Ahs)[16 * 528] = (uint16_t (*)[16 * 528])smem;  // stride 528: conflict-free
  float* gates = (float*)(smem + 33792);

  const int wv = tid >> 6, ln = tid & 63;
  const int q = ln >> 4, l16 = ln & 15;
  const int bg = blockIdx.x >> 4, cg = blockIdx.x & 15;
  const int N0 = cg * 128;

  // B fragments resident: wave wv owns n-cols N0 + wv*32 .. +32
  bf16x8 Bfrag[16][2];
#pragma unroll
  for (int kc = 0; kc < 16; ++kc)
#pragma unroll
    for (int nt = 0; nt < 2; ++nt) {
      int n = N0 + wv * 32 + nt * 16 + l16;
      Bfrag[kc][nt] = *(const bf16x8*)(wht + (size_t)n * 512 + kc * 32 + q * 8);
    }
  float breg[2];
#pragma unroll
  for (int nt = 0; nt < 2; ++nt) breg[nt] = biasp[N0 + wv * 32 + nt * 16 + l16];

  const int prow = tid >> 4;                // poll row 0..15
  const int pseg = tid & 15;                // 16B segment within 256B chunk
  const int erow = ln >> 2;
  const int es = ln & 3;
  float creg[2] = {0.f, 0.f};

  // zero Ahs[0] (t=0 state h=0)
  for (int i = tid; i < 4224; i += 256) ((uint32_t*)Ahs[0])[i] = 0;

  // monotone producer frontier: all Mb <= frontier are at the coherence point.
  // Fuel-bounded: on starvation we proceed (wrong data beats a hang).
  int frontier = -1;
  auto gate = [&](int m) {
    int fuel = 1 << 13;
    while (frontier < m) {
      uint32_t v;
      asm volatile("global_load_dword %0, %1, off sc0 sc1\n\t"
                   "s_waitcnt vmcnt(0)"
                   : "=v"(v) : "v"(dcnt + (frontier + 1)) : "memory");
      if (v >= 16u) { ++frontier; continue; }
      if (--fuel <= 0) { ++frontier; continue; }
      __builtin_amdgcn_s_sleep(2);
    }
  };

  gate(0);
  // register prefetch of pre strip for t=0
  uint16_t pr[8];
#pragma unroll
  for (int nt = 0; nt < 2; ++nt)
#pragma unroll
    for (int r = 0; r < 4; ++r)
      pr[nt * 4 + r] = pre[(size_t)(bg * 16 + q * 4 + r) * 2048 + N0 + wv * 32 + nt * 16 + l16];

  for (int t = 0; t < 256; ++t) {
    if (t > 0) {
      const char* sb = ring + (size_t)((t - 1) & 1) * 262144 + (size_t)bg * 65536;
      const char* base = sb + prow * 2048 + pseg * 16;
      const uint32_t want = (uint32_t)t;
      u32x4 u0, u1, u2, u3, u4, u5, u6, u7;
      int pfuel = 1 << 13;
      for (;;) {
        asm volatile(
            "global_load_dwordx4 %0, %8, off sc0 sc1\n\t"
            "global_load_dwordx4 %1, %8, off offset:256 sc0 sc1\n\t"
            "global_load_dwordx4 %2, %8, off offset:512 sc0 sc1\n\t"
            "global_load_dwordx4 %3, %8, off offset:768 sc0 sc1\n\t"
            "global_load_dwordx4 %4, %8, off offset:1024 sc0 sc1\n\t"
            "global_load_dwordx4 %5, %8, off offset:1280 sc0 sc1\n\t"
            "global_load_dwordx4 %6, %8, off offset:1536 sc0 sc1\n\t"
            "global_load_dwordx4 %7, %8, off offset:1792 sc0 sc1\n\t"
            "s_waitcnt vmcnt(0)"
            : "=v"(u0), "=v"(u1), "=v"(u2), "=v"(u3),
              "=v"(u4), "=v"(u5), "=v"(u6), "=v"(u7)
            : "v"(base)
            : "memory");
        bool ok = (u0.y == want) && (u0.w == want) && (u1.y == want) && (u1.w == want) &&
                  (u2.y == want) && (u2.w == want) && (u3.y == want) && (u3.w == want) &&
                  (u4.y == want) && (u4.w == want) && (u5.y == want) && (u5.w == want) &&
                  (u6.y == want) && (u6.w == want) && (u7.y == want) && (u7.w == want);
        if (ok) break;
        if (--pfuel <= 0) break;
        __builtin_amdgcn_s_sleep(1);
      }
      // stage payloads: col = 4*pseg + 64*j, contiguous 4 cols per u32x4
      uint16_t* dr = Ahs[t & 1] + prow * 528 + pseg * 4;
      *(ull*)(dr +   0) = (ull)u0.x | ((ull)u0.z << 32);
      *(ull*)(dr +  64) = (ull)u1.x | ((ull)u1.z << 32);
      *(ull*)(dr + 128) = (ull)u2.x | ((ull)u2.z << 32);
      *(ull*)(dr + 192) = (ull)u3.x | ((ull)u3.z << 32);
      *(ull*)(dr + 256) = (ull)u4.x | ((ull)u4.z << 32);
      *(ull*)(dr + 320) = (ull)u5.x | ((ull)u5.z << 32);
      *(ull*)(dr + 384) = (ull)u6.x | ((ull)u6.z << 32);
      *(ull*)(dr + 448) = (ull)u7.x | ((ull)u7.z << 32);
    }
    __syncthreads();  // the one barrier per step

    // MFMA [16 x 512] x [512 x 32] per wave, 2 chains of 8
    const uint16_t* Ab = Ahs[t & 1];
    floatx4 a0[2] = {}, a1[2] = {};
#pragma unroll
    for (int kc = 0; kc < 8; ++kc) {
      bf16x8 a = *(const bf16x8*)(Ab + l16 * 528 + kc * 32 + q * 8);
#pragma unroll
      for (int nt = 0; nt < 2; ++nt)
        a0[nt] = __builtin_amdgcn_mfma_f32_16x16x32_bf16(a, Bfrag[kc][nt], a0[nt], 0, 0, 0);
    }
#pragma unroll
    for (int kc = 8; kc < 16; ++kc) {
      bf16x8 a = *(const bf16x8*)(Ab + l16 * 528 + kc * 32 + q * 8);
#pragma unroll
      for (int nt = 0; nt < 2; ++nt)
        a1[nt] = __builtin_amdgcn_mfma_f32_16x16x32_bf16(a, Bfrag[kc][nt], a1[nt], 0, 0, 0);
    }

    // gates = acc + bias + pre (registers, wave-local columns)
#pragma unroll
    for (int nt = 0; nt < 2; ++nt) {
      int n_l = wv * 32 + nt * 16 + l16;
      floatx4 s = a0[nt] + a1[nt];
#pragma unroll
      for (int r = 0; r < 4; ++r) {
        int row = q * 4 + r;
        gates[row * 132 + n_l] = s[r] + breg[nt] + bf2f(pr[nt * 4 + r]);
      }
    }
    // wave-local LDS exchange: compiler inserts lgkmcnt wait, no barrier

    // epilogue: 2 h-units per lane; tagged 8B device-scope store into ring[t&1]
    {
      float4 v0 = *(const float4*)(gates + erow * 132 + wv * 32 + es * 8);
      float4 v1 = *(const float4*)(gates + erow * 132 + wv * 32 + es * 8 + 4);
      float f0 = sigm(v0.x), i0 = sigm(v0.y), g0 = tanh_s(v0.z), o0 = sigm(v0.w);
      float f1 = sigm(v1.x), i1 = sigm(v1.y), g1 = tanh_s(v1.z), o1 = sigm(v1.w);
      float c0 = f0 * creg[0] + i0 * g0; creg[0] = c0;
      float c1 = f1 * creg[1] + i1 * g1; creg[1] = c1;
      float h0 = o0 * tanh_s(c0), h1 = o1 * tanh_s(c1);
      char* sbw = ring + (size_t)(t & 1) * 262144 + (size_t)bg * 65536;
      int pair = cg * 16 + wv * 4 + es;
      ull pk = (ull)((uint32_t)f2bf(h0) | ((uint32_t)f2bf(h1) << 16)) |
               ((ull)(uint32_t)(t + 1) << 32);
      __hip_atomic_store((ull*)(sbw + erow * 2048 + pair * 8),
                         pk, __ATOMIC_RELAXED, __HIP_MEMORY_SCOPE_AGENT);
      if (t == 255) {
        size_t idx = (size_t)(bg * 16 + erow) * 512 + cg * 32 + wv * 8 + es * 2;
        hfin[idx] = h0; hfin[idx + 1] = h1;
        cfin[idx] = c0; cfin[idx + 1] = c1;
      }
    }

    // register prefetch of pre strip for t+1, gated on producer frontier
    // (steady state after drain: frontier far ahead -> gate is one cheap check)
    if (t < 255) {
      int tn = t + 1;
      gate(tn >> 1);
#pragma unroll
      for (int nt = 0; nt < 2; ++nt)
#pragma unroll
        for (int r = 0; r < 4; ++r)
          pr[nt * 4 + r] = pre[(size_t)(tn * 64 + bg * 16 + q * 4 + r) * 2048 + N0 + wv * 32 + nt * 16 + l16];
    }
  }
}

// ---------- 6. final: out = h @ W_lin + b_lin; copy h, c ----------
__global__ __launch_bounds__(256) void k_final(const float* __restrict__ h, const float* __restrict__ c,
                                               const float* __restrict__ wl, const float* __restrict__ bl,
                                               float* __restrict__ out) {
  __shared__ float red[256];
  int b = blockIdx.x, t = threadIdx.x;
  const float* hb = h + (size_t)b * 512;
  if (t < 128) {
    ((float4*)(out + 320 + (size_t)b * 512))[t] = ((const float4*)hb)[t];
    ((float4*)(out + 320 + 32768 + (size_t)b * 512))[t] = ((const float4*)(c + (size_t)b * 512))[t];
  }
  float h0 = hb[t], h1 = hb[t + 256];
  for (int o = 0; o < 5; ++o) {
    red[t] = h0 * wl[t * 5 + o] + h1 * wl[(t + 256) * 5 + o];
    __syncthreads();
    for (int s = 128; s > 0; s >>= 1) {
      if (t < s) red[t] += red[t + s];
      __syncthreads();
    }
    if (t == 0) out[b * 5 + o] = red[0] + bl[o];
    __syncthreads();
  }
}

// ---------- launch ----------
extern "C" void kernel_launch(void* const* d_in, const int* in_sizes, int n_in,
                              void* d_out, int out_size, void* d_ws, size_t ws_size,
                              hipStream_t stream) {
  const int*   x   = (const int*)d_in[0];
  const float* emb = (const float*)d_in[1];
  const float* wfx = (const float*)d_in[2];
  const float* wfh = (const float*)d_in[3];
  const float* bf_ = (const float*)d_in[4];
  const float* wix = (const float*)d_in[5];
  const float* wih = (const float*)d_in[6];
  const float* bi_ = (const float*)d_in[7];
  const float* wgx = (const float*)d_in[8];
  const float* wgh = (const float*)d_in[9];
  const float* bg_ = (const float*)d_in[10];
  const float* wox = (const float*)d_in[11];
  const float* woh = (const float*)d_in[12];
  const float* bo_ = (const float*)d_in[13];
  const float* wl  = (const float*)d_in[14];
  const float* bl  = (const float*)d_in[15];
  float* out = (float*)d_out;
  char* ws = (char*)d_ws;

  uint16_t* embbf = (uint16_t*)(ws + OFF_EMB);
  uint16_t* wxt   = (uint16_t*)(ws + OFF_WXT);
  uint16_t* wht   = (uint16_t*)(ws + OFF_WHT);
  float*    bias  = (float*)(ws + OFF_BIAS);
  uint16_t* pre   = (uint16_t*)(ws + OFF_PRE);
  float*    hfin  = (float*)(ws + OFF_HF);
  float*    cfin  = (float*)(ws + OFF_CF);
  unsigned* dcnt  = (unsigned*)(ws + OFF_CNT);

  hipLaunchKernelGGL(k_emb_cvt, dim3(6250), dim3(256), 0, stream, emb, embbf);
  hipLaunchKernelGGL(k_wt, dim3(64, 32), dim3(256), 0, stream, wfx, wix, wgx, wox, 4096, wxt);
  hipLaunchKernelGGL(k_wt, dim3(8, 32), dim3(256), 0, stream, wfh, wih, wgh, woh, 512, wht);
  hipLaunchKernelGGL(k_bias, dim3(8), dim3(256), 0, stream, bf_, bi_, bg_, bo_, bias, dcnt);
  hipLaunchKernelGGL(k_fused, dim3(2048), dim3(256), 0, stream, embbf, x, wxt, pre,
                     ws + OFF_RING, wht, bias, hfin, cfin, dcnt);
  hipLaunchKernelGGL(k_final, dim3(64), dim3(256), 0, stream, hfin, cfin, wl, bl, out);
}

// Round 7
// 1112.408 us; speedup vs baseline: 1.3094x; 1.0830x over previous
//
#include <hip/hip_runtime.h>
#include <stdint.h>

#define DEVI __device__ __forceinline__
typedef unsigned long long ull;

typedef __bf16 bf16x8 __attribute__((ext_vector_type(8)));
typedef float floatx4 __attribute__((ext_vector_type(4)));
typedef unsigned int u32x4 __attribute__((ext_vector_type(4)));

// ---------- helpers ----------
DEVI uint16_t f2bf(float f) {
  union { float f; uint32_t u; } c; c.f = f;
  uint32_t u = c.u;
  return (uint16_t)((u + 0x7fffu + ((u >> 16) & 1u)) >> 16);  // RNE
}
DEVI float bf2f(uint16_t h) {
  union { uint32_t u; float f; } c; c.u = ((uint32_t)h) << 16;
  return c.f;
}
DEVI void load_lds_16(const void* g, void* l) {
  __builtin_amdgcn_global_load_lds(
      (const __attribute__((address_space(1))) void*)g,
      (__attribute__((address_space(3))) void*)l, 16, 0, 0);
}
DEVI float sigm(float x) { return 1.f / (1.f + __expf(-x)); }
DEVI float tanh_s(float x) {
  float xc = fminf(fmaxf(x, -15.f), 15.f);
  float e = __expf(2.f * xc);
  return (e - 1.f) / (e + 1.f);
}

// ---------- workspace layout (bytes) ----------
// pre [256][64][2048] bf16; tagged-h slab for step t>=2 aliases pre[t-2]
// (first 32KB of each bg's 64KB row-group; serial k_gemm->k_rec dispatch
// boundary flushes L2, and slab accesses are cache-bypassing).
// Slab(t,bg): [16 rows][2048B], pair p at p*8 = [bf16x2 payload | tag=t+1].
static constexpr size_t OFF_EMB    = 0;                        // [50000][256] bf16
static constexpr size_t OFF_WXT    = 25600000;                 // [2048][4096] bf16
static constexpr size_t OFF_WHT    = OFF_WXT + 16777216;       // [2048][512] bf16
static constexpr size_t OFF_BIAS   = OFF_WHT + 2097152;        // [2048] f32
static constexpr size_t OFF_PRE    = OFF_BIAS + 8192;          // [256][64][2048] bf16
static constexpr size_t OFF_HF     = OFF_PRE + 67108864 + 4096;
static constexpr size_t OFF_CF     = OFF_HF + 131072;
static constexpr size_t OFF_CNT    = OFF_CF + 131072;          // (unused this round)
static constexpr size_t OFF_SLAB01 = OFF_CNT + 4096;           // 2 x 262144 slabs t=0,1 (poison!=tag)

// ---------- 1. embedding -> bf16, row 0 zeroed ----------
__global__ __launch_bounds__(256) void k_emb_cvt(const float* __restrict__ emb,
                                                 uint16_t* __restrict__ dst) {
  size_t tid = (size_t)blockIdx.x * 256 + threadIdx.x;
  size_t e = tid * 8;
  int v = (int)(e >> 8);
  const float4* s = (const float4*)(emb + e);
  float4 f0 = s[0], f1 = s[1];
  if (v == 0) { f0 = make_float4(0.f, 0.f, 0.f, 0.f); f1 = f0; }
  uint32_t w0 = f2bf(f0.x) | ((uint32_t)f2bf(f0.y) << 16);
  uint32_t w1 = f2bf(f0.z) | ((uint32_t)f2bf(f0.w) << 16);
  uint32_t w2 = f2bf(f1.x) | ((uint32_t)f2bf(f1.y) << 16);
  uint32_t w3 = f2bf(f1.z) | ((uint32_t)f2bf(f1.w) << 16);
  *(uint4*)(dst + e) = make_uint4(w0, w1, w2, w3);
}

// ---------- 2. weight transpose+convert: W_g[K][512] -> dst[n=h*4+g][K] bf16 ----------
__global__ __launch_bounds__(256) void k_wt(const float* __restrict__ w0, const float* __restrict__ w1,
                                            const float* __restrict__ w2, const float* __restrict__ w3,
                                            int K, uint16_t* __restrict__ dst) {
  __shared__ float tile[64 * 64];
  int k0 = blockIdx.x * 64;
  int n0 = blockIdx.y * 64;
  int h0 = blockIdx.y * 16;
  int g = threadIdx.x >> 6, di = threadIdx.x & 63;
  const float* w = (g == 0) ? w0 : (g == 1) ? w1 : (g == 2) ? w2 : w3;
  const float4* src = (const float4*)(w + (size_t)(k0 + di) * 512 + h0);
  float4 a = src[0], b = src[1], c = src[2], d = src[3];
  float vals[16] = {a.x, a.y, a.z, a.w, b.x, b.y, b.z, b.w,
                    c.x, c.y, c.z, c.w, d.x, d.y, d.z, d.w};
#pragma unroll
  for (int dh = 0; dh < 16; ++dh) tile[(dh * 4 + g) * 64 + di] = vals[dh];
  __syncthreads();
  int nl = threadIdx.x >> 2, ch = threadIdx.x & 3;
  uint32_t wb[8];
#pragma unroll
  for (int j = 0; j < 8; ++j) {
    float lo = tile[nl * 64 + ch * 16 + j * 2];
    float hi = tile[nl * 64 + ch * 16 + j * 2 + 1];
    wb[j] = f2bf(lo) | ((uint32_t)f2bf(hi) << 16);
  }
  uint4* dp = (uint4*)(dst + (size_t)(n0 + nl) * K + k0 + ch * 16);
  dp[0] = make_uint4(wb[0], wb[1], wb[2], wb[3]);
  dp[1] = make_uint4(wb[4], wb[5], wb[6], wb[7]);
}

// ---------- 3. bias pack ----------
__global__ __launch_bounds__(256) void k_bias(const float* __restrict__ b0, const float* __restrict__ b1,
                                              const float* __restrict__ b2, const float* __restrict__ b3,
                                              float* __restrict__ dst) {
  int n = blockIdx.x * 256 + threadIdx.x;
  int h = n >> 2, g = n & 3;
  const float* b = (g == 0) ? b0 : (g == 1) ? b1 : (g == 2) ? b2 : b3;
  dst[n] = b[h];
}

// ---------- 4. gather-GEMM (unchanged, known-good) ----------
__global__ __launch_bounds__(256) void k_gemm(const uint16_t* __restrict__ embbf,
                                              const int* __restrict__ x,
                                              const uint16_t* __restrict__ wxt,
                                              uint16_t* __restrict__ pre) {
  __shared__ uint16_t As[128 * 64];
  __shared__ uint16_t Bs[128 * 64];
  const int tid = threadIdx.x;
  const int wv = tid >> 6, ln = tid & 63;
  const int wm = wv >> 1, wn = wv & 1;
  const int M0 = blockIdx.x * 128, N0 = blockIdx.y * 128;
  const int srow = ln >> 3, schunk = ln & 7;

  const int* xrow[4];
  const uint16_t* bbase[4];
  uint16_t* ldsA[4];
  uint16_t* ldsB[4];
#pragma unroll
  for (int j = 0; j < 4; ++j) {
    int r = j * 32 + wv * 8 + srow;
    int m = M0 + r;
    int t = m >> 6, b = m & 63;
    xrow[j] = x + b * 4096 + t;
    bbase[j] = wxt + (size_t)(N0 + r) * 4096 + schunk * 8;
    ldsA[j] = As + (j * 32 + wv * 8) * 64;
    ldsB[j] = Bs + (j * 32 + wv * 8) * 64;
  }

  const int q = ln >> 4, l16 = ln & 15;
  int aoff[4], boff[4];
#pragma unroll
  for (int mt = 0; mt < 4; ++mt) aoff[mt] = (wm * 64 + mt * 16 + l16) * 64 + q * 8;
#pragma unroll
  for (int nt = 0; nt < 4; ++nt) boff[nt] = (wn * 64 + nt * 16 + l16) * 64 + q * 8;

  floatx4 acc[4][4] = {};

  for (int p = 0; p < 16; ++p) {
    const uint16_t* abase[4];
#pragma unroll
    for (int j = 0; j < 4; ++j) {
      int idx = xrow[j][p << 8];
      abase[j] = embbf + (size_t)idx * 256 + schunk * 8;
    }
#pragma unroll 1
    for (int ki = 0; ki < 4; ++ki) {
      __syncthreads();
#pragma unroll
      for (int j = 0; j < 4; ++j) load_lds_16(abase[j] + ki * 64, ldsA[j]);
#pragma unroll
      for (int j = 0; j < 4; ++j) load_lds_16(bbase[j] + p * 256 + ki * 64, ldsB[j]);
      __syncthreads();
#pragma unroll
      for (int kk = 0; kk < 2; ++kk) {
        bf16x8 a[4];
#pragma unroll
        for (int mt = 0; mt < 4; ++mt) a[mt] = *(const bf16x8*)(As + aoff[mt] + kk * 32);
#pragma unroll
        for (int nt = 0; nt < 4; ++nt) {
          bf16x8 bv = *(const bf16x8*)(Bs + boff[nt] + kk * 32);
#pragma unroll
          for (int mt = 0; mt < 4; ++mt)
            acc[mt][nt] = __builtin_amdgcn_mfma_f32_16x16x32_bf16(a[mt], bv, acc[mt][nt], 0, 0, 0);
        }
      }
    }
  }

#pragma unroll
  for (int mt = 0; mt < 4; ++mt) {
    int mg = M0 + wm * 64 + mt * 16 + q * 4;
#pragma unroll
    for (int nt = 0; nt < 4; ++nt) {
      int ng = N0 + wn * 64 + nt * 16 + l16;
#pragma unroll
      for (int r = 0; r < 4; ++r)
        pre[(size_t)(mg + r) * 2048 + ng] = f2bf(acc[mt][nt][r]);
    }
  }
}

// ---------- 5. persistent recurrence: tagged single-RT exchange ----------
// r0-proven body (573us) + critical-path surgery:
//  (a) pre-strip prefetch double-buffered (pr/prn) and ISSUED EARLY (right
//      after staging) instead of at loop end — vmcnt retires in-order, so the
//      old placement serialized ~900cy of cold HBM latency into the next
//      poll's vmcnt(0) every step.
//  (b) raw s_barrier with lgkmcnt(0) only (NOT __syncthreads, which drains
//      vmcnt(0)) — the prefetch and h-store ack ride across the barrier and
//      retire under MFMA+epilogue. Barrier only needs LDS staging visibility.
//  (c) first poll retry without s_sleep.
__global__ __launch_bounds__(256) void k_rec(const uint16_t* pre,  // aliased by slabs
                                             char* preb,
                                             char* scratch,
                                             const uint16_t* __restrict__ wht,
                                             const float* __restrict__ biasp,
                                             float* __restrict__ hfin,
                                             float* __restrict__ cfin) {
  __shared__ uint16_t Ahs[2][16 * 528];     // stride 528: conflict-free b64 writes + b128 reads
  __shared__ float gates[16 * 132];

  const int tid = threadIdx.x;
  const int wv = tid >> 6, ln = tid & 63;
  const int q = ln >> 4, l16 = ln & 15;
  const int bg = blockIdx.x >> 4, cg = blockIdx.x & 15;
  const int N0 = cg * 128;

  // B fragments resident: wave wv owns n-cols N0 + wv*32 .. +32
  bf16x8 Bfrag[16][2];
#pragma unroll
  for (int kc = 0; kc < 16; ++kc)
#pragma unroll
    for (int nt = 0; nt < 2; ++nt) {
      int n = N0 + wv * 32 + nt * 16 + l16;
      Bfrag[kc][nt] = *(const bf16x8*)(wht + (size_t)n * 512 + kc * 32 + q * 8);
    }
  float breg[2];
#pragma unroll
  for (int nt = 0; nt < 2; ++nt) breg[nt] = biasp[N0 + wv * 32 + nt * 16 + l16];

  const int prow = tid >> 4;                // poll row 0..15
  const int pseg = tid & 15;                // 16B segment within 256B chunk
  const int erow = ln >> 2;
  const int es = ln & 3;
  float creg[2] = {0.f, 0.f};

  // zero Ahs[0] (t=0 state h=0)
  for (int i = tid; i < 4224; i += 256) ((uint32_t*)Ahs[0])[i] = 0;

  // register prefetch of pre strip for t=0 (current) — prn holds next
  uint16_t pr[8], prn[8];
#pragma unroll
  for (int nt = 0; nt < 2; ++nt)
#pragma unroll
    for (int r = 0; r < 4; ++r)
      pr[nt * 4 + r] = pre[(size_t)(bg * 16 + q * 4 + r) * 2048 + N0 + wv * 32 + nt * 16 + l16];

  for (int t = 0; t < 256; ++t) {
    if (t > 0) {
      const char* sb = ((t - 1) < 2 ? scratch + (size_t)(t - 1) * 262144
                                    : preb + (size_t)(t - 3) * 262144) + (size_t)bg * 65536;
      const char* base = sb + prow * 2048 + pseg * 16;
      const uint32_t want = (uint32_t)t;
      u32x4 u0, u1, u2, u3, u4, u5, u6, u7;
      int misses = 0;
      for (;;) {
        asm volatile(
            "global_load_dwordx4 %0, %8, off sc0 sc1\n\t"
            "global_load_dwordx4 %1, %8, off offset:256 sc0 sc1\n\t"
            "global_load_dwordx4 %2, %8, off offset:512 sc0 sc1\n\t"
            "global_load_dwordx4 %3, %8, off offset:768 sc0 sc1\n\t"
            "global_load_dwordx4 %4, %8, off offset:1024 sc0 sc1\n\t"
            "global_load_dwordx4 %5, %8, off offset:1280 sc0 sc1\n\t"
            "global_load_dwordx4 %6, %8, off offset:1536 sc0 sc1\n\t"
            "global_load_dwordx4 %7, %8, off offset:1792 sc0 sc1\n\t"
            "s_waitcnt vmcnt(0)"
            : "=v"(u0), "=v"(u1), "=v"(u2), "=v"(u3),
              "=v"(u4), "=v"(u5), "=v"(u6), "=v"(u7)
            : "v"(base)
            : "memory");
        bool ok = (u0.y == want) && (u0.w == want) && (u1.y == want) && (u1.w == want) &&
                  (u2.y == want) && (u2.w == want) && (u3.y == want) && (u3.w == want) &&
                  (u4.y == want) && (u4.w == want) && (u5.y == want) && (u5.w == want) &&
                  (u6.y == want) && (u6.w == want) && (u7.y == want) && (u7.w == want);
        if (ok) break;
        if (misses++) __builtin_amdgcn_s_sleep(1);   // first retry immediate
      }
      // stage payloads: col = 4*pseg + 64*j, contiguous 4 cols per u32x4
      uint16_t* dr = Ahs[t & 1] + prow * 528 + pseg * 4;
      *(ull*)(dr +   0) = (ull)u0.x | ((ull)u0.z << 32);
      *(ull*)(dr +  64) = (ull)u1.x | ((ull)u1.z << 32);
      *(ull*)(dr + 128) = (ull)u2.x | ((ull)u2.z << 32);
      *(ull*)(dr + 192) = (ull)u3.x | ((ull)u3.z << 32);
      *(ull*)(dr + 256) = (ull)u4.x | ((ull)u4.z << 32);
      *(ull*)(dr + 320) = (ull)u5.x | ((ull)u5.z << 32);
      *(ull*)(dr + 384) = (ull)u6.x | ((ull)u6.z << 32);
      *(ull*)(dr + 448) = (ull)u7.x | ((ull)u7.z << 32);
    }

    // EARLY prefetch of pre strip for t+1 (issued before the barrier; rides
    // across it and retires under MFMA+epilogue; copied to pr at loop end)
    if (t < 255) {
      int tn = t + 1;
#pragma unroll
      for (int nt = 0; nt < 2; ++nt)
#pragma unroll
        for (int r = 0; r < 4; ++r)
          prn[nt * 4 + r] = pre[(size_t)(tn * 64 + bg * 16 + q * 4 + r) * 2048 + N0 + wv * 32 + nt * 16 + l16];
    }

    // raw barrier: drain LDS (staging visibility) but NOT vmcnt — prefetch
    // and previous h-store stay in flight (nothing cross-wave rides on them)
    asm volatile("s_waitcnt lgkmcnt(0)" ::: "memory");
    __builtin_amdgcn_s_barrier();
    __builtin_amdgcn_sched_barrier(0);

    // MFMA [16 x 512] x [512 x 32] per wave, 2 chains of 8
    const uint16_t* Ab = Ahs[t & 1];
    floatx4 a0[2] = {}, a1[2] = {};
#pragma unroll
    for (int kc = 0; kc < 8; ++kc) {
      bf16x8 a = *(const bf16x8*)(Ab + l16 * 528 + kc * 32 + q * 8);
#pragma unroll
      for (int nt = 0; nt < 2; ++nt)
        a0[nt] = __builtin_amdgcn_mfma_f32_16x16x32_bf16(a, Bfrag[kc][nt], a0[nt], 0, 0, 0);
    }
#pragma unroll
    for (int kc = 8; kc < 16; ++kc) {
      bf16x8 a = *(const bf16x8*)(Ab + l16 * 528 + kc * 32 + q * 8);
#pragma unroll
      for (int nt = 0; nt < 2; ++nt)
        a1[nt] = __builtin_amdgcn_mfma_f32_16x16x32_bf16(a, Bfrag[kc][nt], a1[nt], 0, 0, 0);
    }

    // gates = acc + bias + pre (registers, wave-local columns)
#pragma unroll
    for (int nt = 0; nt < 2; ++nt) {
      int n_l = wv * 32 + nt * 16 + l16;
      floatx4 s = a0[nt] + a1[nt];
#pragma unroll
      for (int r = 0; r < 4; ++r) {
        int row = q * 4 + r;
        gates[row * 132 + n_l] = s[r] + breg[nt] + bf2f(pr[nt * 4 + r]);
      }
    }
    // wave-local LDS exchange: compiler inserts lgkmcnt wait, no barrier

    // epilogue: 2 h-units per lane; tagged 8B agent store
    {
      float4 v0 = *(const float4*)(gates + erow * 132 + wv * 32 + es * 8);
      float4 v1 = *(const float4*)(gates + erow * 132 + wv * 32 + es * 8 + 4);
      float f0 = sigm(v0.x), i0 = sigm(v0.y), g0 = tanh_s(v0.z), o0 = sigm(v0.w);
      float f1 = sigm(v1.x), i1 = sigm(v1.y), g1 = tanh_s(v1.z), o1 = sigm(v1.w);
      float c0 = f0 * creg[0] + i0 * g0; creg[0] = c0;
      float c1 = f1 * creg[1] + i1 * g1; creg[1] = c1;
      float h0 = o0 * tanh_s(c0), h1 = o1 * tanh_s(c1);
      char* sbw = (t < 2 ? scratch + (size_t)t * 262144
                         : preb + (size_t)(t - 2) * 262144) + (size_t)bg * 65536;
      int pair = cg * 16 + wv * 4 + es;
      ull pk = (ull)((uint32_t)f2bf(h0) | ((uint32_t)f2bf(h1) << 16)) |
               ((ull)(uint32_t)(t + 1) << 32);
      __hip_atomic_store((ull*)(sbw + erow * 2048 + pair * 8),
                         pk, __ATOMIC_RELAXED, __HIP_MEMORY_SCOPE_AGENT);
      if (t == 255) {
        size_t idx = (size_t)(bg * 16 + erow) * 512 + cg * 32 + wv * 8 + es * 2;
        hfin[idx] = h0; hfin[idx + 1] = h1;
        cfin[idx] = c0; cfin[idx + 1] = c1;
      }
    }

    // rotate prefetch buffer (compiler inserts a precise vmcnt wait here,
    // ~1500cy after issue — mostly retired)
    if (t < 255) {
#pragma unroll
      for (int j = 0; j < 8; ++j) pr[j] = prn[j];
    }
  }
}

// ---------- 6. final: out = h @ W_lin + b_lin; copy h, c ----------
__global__ __launch_bounds__(256) void k_final(const float* __restrict__ h, const float* __restrict__ c,
                                               const float* __restrict__ wl, const float* __restrict__ bl,
                                               float* __restrict__ out) {
  __shared__ float red[256];
  int b = blockIdx.x, t = threadIdx.x;
  const float* hb = h + (size_t)b * 512;
  if (t < 128) {
    ((float4*)(out + 320 + (size_t)b * 512))[t] = ((const float4*)hb)[t];
    ((float4*)(out + 320 + 32768 + (size_t)b * 512))[t] = ((const float4*)(c + (size_t)b * 512))[t];
  }
  float h0 = hb[t], h1 = hb[t + 256];
  for (int o = 0; o < 5; ++o) {
    red[t] = h0 * wl[t * 5 + o] + h1 * wl[(t + 256) * 5 + o];
    __syncthreads();
    for (int s = 128; s > 0; s >>= 1) {
      if (t < s) red[t] += red[t + s];
      __syncthreads();
    }
    if (t == 0) out[b * 5 + o] = red[0] + bl[o];
    __syncthreads();
  }
}

// ---------- launch ----------
extern "C" void kernel_launch(void* const* d_in, const int* in_sizes, int n_in,
                              void* d_out, int out_size, void* d_ws, size_t ws_size,
                              hipStream_t stream) {
  const int*   x   = (const int*)d_in[0];
  const float* emb = (const float*)d_in[1];
  const float* wfx = (const float*)d_in[2];
  const float* wfh = (const float*)d_in[3];
  const float* bf_ = (const float*)d_in[4];
  const float* wix = (const float*)d_in[5];
  const float* wih = (const float*)d_in[6];
  const float* bi_ = (const float*)d_in[7];
  const float* wgx = (const float*)d_in[8];
  const float* wgh = (const float*)d_in[9];
  const float* bg_ = (const float*)d_in[10];
  const float* wox = (const float*)d_in[11];
  const float* woh = (const float*)d_in[12];
  const float* bo_ = (const float*)d_in[13];
  const float* wl  = (const float*)d_in[14];
  const float* bl  = (const float*)d_in[15];
  float* out = (float*)d_out;
  char* ws = (char*)d_ws;

  uint16_t* embbf = (uint16_t*)(ws + OFF_EMB);
  uint16_t* wxt   = (uint16_t*)(ws + OFF_WXT);
  uint16_t* wht   = (uint16_t*)(ws + OFF_WHT);
  float*    bias  = (float*)(ws + OFF_BIAS);
  uint16_t* pre   = (uint16_t*)(ws + OFF_PRE);
  float*    hfin  = (float*)(ws + OFF_HF);
  float*    cfin  = (float*)(ws + OFF_CF);

  hipLaunchKernelGGL(k_emb_cvt, dim3(6250), dim3(256), 0, stream, emb, embbf);
  hipLaunchKernelGGL(k_wt, dim3(64, 32), dim3(256), 0, stream, wfx, wix, wgx, wox, 4096, wxt);
  hipLaunchKernelGGL(k_wt, dim3(8, 32), dim3(256), 0, stream, wfh, wih, wgh, woh, 512, wht);
  hipLaunchKernelGGL(k_bias, dim3(8), dim3(256), 0, stream, bf_, bi_, bg_, bo_, bias);
  hipLaunchKernelGGL(k_gemm, dim3(128, 16), dim3(256), 0, stream, embbf, x, wxt, pre);
  hipLaunchKernelGGL(k_rec, dim3(64), dim3(256), 0, stream, pre, (char*)(ws + OFF_PRE),
                     ws + OFF_SLAB01, wht, bias, hfin, cfin);
  hipLaunchKernelGGL(k_final, dim3(64), dim3(256), 0, stream, hfin, cfin, wl, bl, out);
}